// Round 15
// baseline (1013.325 us; speedup 1.0000x reference)
//
#include <hip/hip_runtime.h>
#include <hip/hip_bf16.h>

#define H 128
#define NEG 0.01f

typedef __bf16 bf16;
typedef bf16 bf16x4 __attribute__((ext_vector_type(4)));
typedef bf16 bf16x8 __attribute__((ext_vector_type(8)));
typedef float f32x4 __attribute__((ext_vector_type(4)));
typedef float f32x2 __attribute__((ext_vector_type(2)));
typedef unsigned int u32;

// ---- fp8 e4m3 (OCP on gfx950) pack/unpack: 16 elems <-> 16 bytes (uint4) ----
__device__ __forceinline__ void dec16(uint4 p, float f[16]) {
    f32x2 a0 = __builtin_amdgcn_cvt_pk_f32_fp8(p.x, false);
    f32x2 a1 = __builtin_amdgcn_cvt_pk_f32_fp8(p.x, true);
    f32x2 b0 = __builtin_amdgcn_cvt_pk_f32_fp8(p.y, false);
    f32x2 b1 = __builtin_amdgcn_cvt_pk_f32_fp8(p.y, true);
    f32x2 c0 = __builtin_amdgcn_cvt_pk_f32_fp8(p.z, false);
    f32x2 c1 = __builtin_amdgcn_cvt_pk_f32_fp8(p.z, true);
    f32x2 d0 = __builtin_amdgcn_cvt_pk_f32_fp8(p.w, false);
    f32x2 d1 = __builtin_amdgcn_cvt_pk_f32_fp8(p.w, true);
    f[0]=a0[0];  f[1]=a0[1];  f[2]=a1[0];  f[3]=a1[1];
    f[4]=b0[0];  f[5]=b0[1];  f[6]=b1[0];  f[7]=b1[1];
    f[8]=c0[0];  f[9]=c0[1];  f[10]=c1[0]; f[11]=c1[1];
    f[12]=d0[0]; f[13]=d0[1]; f[14]=d1[0]; f[15]=d1[1];
}
__device__ __forceinline__ uint4 enc16(const float f[16]) {
    int a = 0, b = 0, c = 0, d = 0;
    a = __builtin_amdgcn_cvt_pk_fp8_f32(f[0],  f[1],  a, false);
    a = __builtin_amdgcn_cvt_pk_fp8_f32(f[2],  f[3],  a, true);
    b = __builtin_amdgcn_cvt_pk_fp8_f32(f[4],  f[5],  b, false);
    b = __builtin_amdgcn_cvt_pk_fp8_f32(f[6],  f[7],  b, true);
    c = __builtin_amdgcn_cvt_pk_fp8_f32(f[8],  f[9],  c, false);
    c = __builtin_amdgcn_cvt_pk_fp8_f32(f[10], f[11], c, true);
    d = __builtin_amdgcn_cvt_pk_fp8_f32(f[12], f[13], d, false);
    d = __builtin_amdgcn_cvt_pk_fp8_f32(f[14], f[15], d, true);
    uint4 r; r.x = (u32)a; r.y = (u32)b; r.z = (u32)c; r.w = (u32)d; return r;
}

// ---- edge-batch helpers: 16-lane group, 2 halves x 4 loads = 8 edges/batch ----
struct Batch { uint4 x[4]; float w[4]; };

__device__ __forceinline__ void load_batch(const uint4* __restrict__ tab,
                                           const int* __restrict__ ssrc,
                                           int base, int e1, int half, int l8, Batch& B) {
#pragma unroll
    for (int j = 0; j < 4; j++) {
        int e = base + j * 2 + half;
        B.w[j] = (e < e1) ? 1.0f : 0.0f;
        int id = ssrc[e < e1 ? e : e1 - 1];
        B.x[j] = tab[(size_t)id * 8 + l8];
    }
}

__device__ __forceinline__ void consume_batch(const Batch& B, float acc[16]) {
#pragma unroll
    for (int j = 0; j < 4; j++) {
        float f[16];
        dec16(B.x[j], f);
#pragma unroll
        for (int k = 0; k < 16; k++) acc[k] = fmaf(B.w[j], f[k], acc[k]);
    }
}

// ---------------- setup: in-degree histogram + chunk partials + weight pre-transpose ----------------
// part[c] = #edges with dst in chunk c (raw sums; scan23 does the prefix) -> k_scan1 deleted.

__global__ void k_setup(const int* __restrict__ dst, int* __restrict__ cnt, int* __restrict__ part,
                        int e, const float* __restrict__ Wn, const float* __restrict__ Wg,
                        bf16* __restrict__ WnT, bf16* __restrict__ WgT) {
    int i = blockIdx.x * 256 + threadIdx.x;
    if (i < e) {
        int d = dst[i];
        atomicAdd(&cnt[d], 1);
        atomicAdd(&part[d >> 8], 1);
    }
    if (i < 256 * 128) {            // WnT[n][k] = Wn[k][n], K=256, Ncol=128
        int n = i >> 8, k = i & 255;
        WnT[i] = (bf16)Wn[k * 128 + n];
    }
    if (i < 128 * 128) {            // WgT[n][k] = Wg[k][n], 128x128
        int n = i >> 7, k = i & 127;
        WgT[i] = (bf16)Wg[k * 128 + n];
    }
}

// ---------------- CSR scan: block-exclusive offset (strided sum of part) + per-element scan ----------------

__global__ void k_scan23(const int* __restrict__ cnt, const int* __restrict__ part,
                         int* __restrict__ row_ptr, int* __restrict__ nxt, int n, int e) {
    __shared__ int red[256];
    __shared__ int sh[256];
    int t = threadIdx.x;
    int i = blockIdx.x * 256 + t;
    // sum of partials strictly before this block
    int s = 0;
    for (int j = t; j < blockIdx.x; j += 256) s += part[j];
    red[t] = s;
    sh[t] = (i < n) ? cnt[i] : 0;
    __syncthreads();
    for (int off = 128; off > 0; off >>= 1) {
        if (t < off) red[t] += red[t + off];
        __syncthreads();
    }
    int blockExcl = red[0];
    // inclusive scan of this block's counts
    for (int off = 1; off < 256; off <<= 1) {
        int v = (t >= off) ? sh[t - off] : 0;
        __syncthreads();
        sh[t] += v;
        __syncthreads();
    }
    int excl = blockExcl + ((t == 0) ? 0 : sh[t - 1]);
    if (i < n) { row_ptr[i] = excl; nxt[i] = excl; }
    if (i == 0) row_ptr[n] = e;
}

// ---------------- fused: bucket-fill (blocks [0,fillBlks)) + GEMM0 (rest) ----------------

__global__ __launch_bounds__(256)
void k_fillgemm0(const int* __restrict__ src, const int* __restrict__ dst,
                 int* __restrict__ nxt, int* __restrict__ ssrc, int e, int fillBlks,
                 const float* __restrict__ A, const bf16* __restrict__ WnT,
                 const float* __restrict__ bias, uint4* __restrict__ Cg,
                 float* __restrict__ colsum, int M) {
    constexpr int K = 256, BM = 64, BN = 128, BK = 64, LDT = BK + 8;
    __shared__ alignas(16) bf16 As[BM][LDT];
    __shared__ alignas(16) bf16 Bs[BN][LDT];
    __shared__ float cs[128];
    const int tid = threadIdx.x;

    if ((int)blockIdx.x < fillBlks) {
        int i = blockIdx.x * 256 + tid;
        if (i < e) {
            int p = atomicAdd(&nxt[dst[i]], 1);
            ssrc[p] = src[i];
        }
        return;
    }

    const int wave = tid >> 6, lane = tid & 63;
    const int sub = lane & 15, rg = lane >> 4;
    const int blockRow = (blockIdx.x - fillBlks) * BM;
    if (tid < 128) cs[tid] = 0.f;

    f32x4 acc[8];
#pragma unroll
    for (int t = 0; t < 8; t++) acc[t] = (f32x4){0.f, 0.f, 0.f, 0.f};

    for (int k0 = 0; k0 < K; k0 += BK) {
#pragma unroll
        for (int it = 0; it < 4; it++) {
            int s = it * 256 + tid;
            int row = s >> 4, f4 = (s & 15) * 4;
            int grow = blockRow + row; if (grow > M - 1) grow = M - 1;
            const float4 v = *(const float4*)(A + (size_t)grow * K + k0 + f4);
            bf16x4 w = { (bf16)v.x, (bf16)v.y, (bf16)v.z, (bf16)v.w };
            *(bf16x4*)&As[row][f4] = w;
        }
        // B: straight bf16 copy from pre-transposed WnT[col][k]
#pragma unroll
        for (int it = 0; it < 4; it++) {
            int s = it * 256 + tid;
            int row = s >> 3, ch = (s & 7) * 8;
            *(bf16x8*)&Bs[row][ch] = *(const bf16x8*)(WnT + (size_t)row * 256 + k0 + ch);
        }
        __syncthreads();
#pragma unroll
        for (int kk = 0; kk < BK; kk += 32) {
            bf16x8 af = *(const bf16x8*)&As[wave * 16 + sub][kk + rg * 8];
#pragma unroll
            for (int t = 0; t < 8; t++) {
                bf16x8 bfv = *(const bf16x8*)&Bs[t * 16 + sub][kk + rg * 8];
                acc[t] = __builtin_amdgcn_mfma_f32_16x16x32_bf16(af, bfv, acc[t], 0, 0, 0);
            }
        }
        __syncthreads();
    }
    // epilogue: bias, colsum, restage tile into LDS (Bs reused) for fp8 packing
    bf16* stg = (bf16*)&Bs[0][0];       // viewed as [64][136]
    const int rbase0 = wave * 16 + rg * 4;
    float lsum[8];
#pragma unroll
    for (int t = 0; t < 8; t++) lsum[t] = 0.f;
#pragma unroll
    for (int r = 0; r < 4; r++) {
        int rowt = rbase0 + r;
        if (blockRow + rowt < M) {
#pragma unroll
            for (int t = 0; t < 8; t++) {
                int col = t * 16 + sub;
                float val = acc[t][r] + bias[col];
                lsum[t] += val;
                stg[rowt * 136 + col] = (bf16)val;
            }
        }
    }
#pragma unroll
    for (int t = 0; t < 8; t++) {
        lsum[t] += __shfl_xor(lsum[t], 16);
        lsum[t] += __shfl_xor(lsum[t], 32);
    }
    if (rg == 0) {
#pragma unroll
        for (int t = 0; t < 8; t++) atomicAdd(&cs[t * 16 + sub], lsum[t]);
    }
    __syncthreads();
    if (tid < 128) atomicAdd(&colsum[tid], cs[tid]);
#pragma unroll
    for (int it = 0; it < 2; it++) {
        int s = it * 256 + tid;      // 0..511: 64 rows x 8 quads
        int row = s >> 3, q = s & 7;
        int grow = blockRow + row;
        if (grow < M) {
            float f[16];
#pragma unroll
            for (int k = 0; k < 16; k++) f[k] = (float)stg[row * 136 + q * 16 + k];
            Cg[(size_t)grow * 8 + q] = enc16(f);
        }
    }
}

// ---------------- agg0: hs[v] = (sum_{u->v} h0[u]) / deg[v]  (fp8 in, fp8 out) ----------------

__global__ __launch_bounds__(256)
void k_agg0(const uint4* __restrict__ hg, const int* __restrict__ row_ptr,
            const int* __restrict__ ssrc, const float* __restrict__ deg,
            uint4* __restrict__ hs, int n) {
    const int tid = threadIdx.x;
    const int gid = tid >> 4, s16 = tid & 15;
    const int half = s16 >> 3, l8 = s16 & 7;
    int v = blockIdx.x * 16 + gid;
    if (v >= n) return;
    int e0 = row_ptr[v], e1 = row_ptr[v + 1];
    float rdeg = 1.0f / deg[v];
    float acc[16];
#pragma unroll
    for (int k = 0; k < 16; k++) acc[k] = 0.f;
    int nbatch = (e1 - e0 + 7) >> 3;
    Batch cur, nxt;
    if (nbatch > 0) load_batch(hg, ssrc, e0, e1, half, l8, cur);
    for (int b = 0; b < nbatch; b++) {
        bool more = (b + 1 < nbatch);
        if (more) load_batch(hg, ssrc, e0 + (b + 1) * 8, e1, half, l8, nxt);
        consume_batch(cur, acc);
        if (more) cur = nxt;
    }
#pragma unroll
    for (int k = 0; k < 16; k++) acc[k] += __shfl_xor(acc[k], 8);
    if (half == 0) {
        float o[16];
#pragma unroll
        for (int k = 0; k < 16; k++) o[k] = acc[k] * rdeg;
        hs[(size_t)v * 8 + l8] = enc16(o);
    }
}

// ---------------- fused layer: A-tile = aggregation, then GEMM + leakyrelu ----------------
// hsin/hsout ping-pong across DISPATCHES (dispatch boundary = the only safe cross-XCD
// flush for plain stores — G16/R13 lesson). When !WRITE_NEXT, the LAST block to finish
// also runs the graph-level finisher (colsum -> Wpred -> Wcls -> softmax) using
// device-scope atomics (coherence-point reads, immune to stale per-XCD L2).

template<bool WRITE_NEXT>
__global__ __launch_bounds__(256)
void k_gemmL(const uint4* __restrict__ hsin, const int* __restrict__ row_ptr,
             const int* __restrict__ ssrc, const float* __restrict__ deg,
             const bf16* __restrict__ WgT, const float* __restrict__ bias,
             uint4* __restrict__ hsout, float* __restrict__ colsum, int M,
             const float* __restrict__ colsumBase, const float* __restrict__ Wpred,
             const float* __restrict__ bpred, const float* __restrict__ Wcls,
             const float* __restrict__ bcls, float* __restrict__ out,
             int* __restrict__ done, int nTotal) {
    constexpr int BM = 64, BN = 128, BK = 128, LDT = BK + 8;
    __shared__ alignas(16) bf16 As[BM][LDT];
    __shared__ alignas(16) bf16 Bs[BN][LDT];
    __shared__ float cs[128];
    __shared__ int lastFlag;
    const int tid = threadIdx.x;
    const int wave = tid >> 6, lane = tid & 63;
    const int sub = lane & 15, rg = lane >> 4;
    const int blockRow = blockIdx.x * BM;
    if (tid < 128) cs[tid] = 0.f;

    // ---- B staging: straight bf16 copy from pre-transposed WgT[col][k] ----
#pragma unroll
    for (int it = 0; it < 8; it++) {
        int s = it * 256 + tid;
        int row = s >> 4, ch = (s & 15) * 8;
        *(bf16x8*)&Bs[row][ch] = *(const bf16x8*)(WgT + (size_t)row * 128 + ch);
    }

    // ---- A-tile via fused aggregation: 16 groups x 16 lanes, 4 rows/group ----
    {
        const int gid = tid >> 4, s16 = tid & 15;
        const int half = s16 >> 3, l8 = s16 & 7;
        for (int i = 0; i < 4; i++) {
            int rowt = gid * 4 + i;
            int v = blockRow + rowt;
            float acc[16], fs[16];
            float d = 0.f;
#pragma unroll
            for (int k = 0; k < 16; k++) { acc[k] = 0.f; fs[k] = 0.f; }
            if (v < M) {
                int e0 = row_ptr[v], e1 = row_ptr[v + 1];
                uint4 sv = hsin[(size_t)v * 8 + l8];   // self row, issued early
                d = deg[v];
                int nbatch = (e1 - e0 + 7) >> 3;
                Batch cur, nxt;
                if (nbatch > 0) load_batch(hsin, ssrc, e0, e1, half, l8, cur);
                for (int b = 0; b < nbatch; b++) {
                    bool more = (b + 1 < nbatch);
                    if (more) load_batch(hsin, ssrc, e0 + (b + 1) * 8, e1, half, l8, nxt);
                    consume_batch(cur, acc);
                    if (more) cur = nxt;
                }
                dec16(sv, fs);
            }
#pragma unroll
            for (int k = 0; k < 16; k++) acc[k] += __shfl_xor(acc[k], 8);
            // self term (hsin is pre-scaled by 1/deg; *deg restores unscaled h)
#pragma unroll
            for (int k = 0; k < 16; k++) acc[k] = fmaf(fs[k], d, acc[k]);
            if (half == 0) {
                bf16x8 w0, w1;
#pragma unroll
                for (int k = 0; k < 8; k++) { w0[k] = (bf16)acc[k]; w1[k] = (bf16)acc[k + 8]; }
                *(bf16x8*)&As[rowt][l8 * 16] = w0;
                *(bf16x8*)&As[rowt][l8 * 16 + 8] = w1;
            }
        }
    }
    __syncthreads();

    // ---- MFMA ----
    f32x4 acc[8];
#pragma unroll
    for (int t = 0; t < 8; t++) acc[t] = (f32x4){0.f, 0.f, 0.f, 0.f};
#pragma unroll
    for (int kk = 0; kk < BK; kk += 32) {
        bf16x8 af = *(const bf16x8*)&As[wave * 16 + sub][kk + rg * 8];
#pragma unroll
        for (int t = 0; t < 8; t++) {
            bf16x8 bfv = *(const bf16x8*)&Bs[t * 16 + sub][kk + rg * 8];
            acc[t] = __builtin_amdgcn_mfma_f32_16x16x32_bf16(af, bfv, acc[t], 0, 0, 0);
        }
    }
    __syncthreads();

    // ---- epilogue: bias + leakyrelu + colsum (+ fp8 pack of val/deg) ----
    bf16* stg = (bf16*)&Bs[0][0];       // viewed as [64][136]
    const int rbase0 = wave * 16 + rg * 4;
    float lsum[8];
#pragma unroll
    for (int t = 0; t < 8; t++) lsum[t] = 0.f;
#pragma unroll
    for (int r = 0; r < 4; r++) {
        int rowt = rbase0 + r;
        int grow = blockRow + rowt;
        if (grow < M) {
            float rd = WRITE_NEXT ? (1.0f / deg[grow]) : 0.f;
#pragma unroll
            for (int t = 0; t < 8; t++) {
                int col = t * 16 + sub;
                float val = acc[t][r] + bias[col];
                val = (val > 0.f) ? val : NEG * val;
                lsum[t] += val;
                if (WRITE_NEXT) stg[rowt * 136 + col] = (bf16)(val * rd);
            }
        }
    }
#pragma unroll
    for (int t = 0; t < 8; t++) {
        lsum[t] += __shfl_xor(lsum[t], 16);
        lsum[t] += __shfl_xor(lsum[t], 32);
    }
    if (rg == 0) {
#pragma unroll
        for (int t = 0; t < 8; t++) atomicAdd(&cs[t * 16 + sub], lsum[t]);
    }
    __syncthreads();
    if (tid < 128) atomicAdd(&colsum[tid], cs[tid]);
    if (WRITE_NEXT) {
#pragma unroll
        for (int it = 0; it < 2; it++) {
            int s = it * 256 + tid;      // 0..511: 64 rows x 8 quads
            int row = s >> 3, q = s & 7;
            int grow = blockRow + row;
            if (grow < M) {
                float f[16];
#pragma unroll
                for (int k = 0; k < 16; k++) f[k] = (float)stg[row * 136 + q * 16 + k];
                hsout[(size_t)grow * 8 + q] = enc16(f);
            }
        }
    } else {
        // ---- last-block finisher ----
        __syncthreads();   // drain all threads' colsum atomics (implies vmcnt(0))
        if (tid == 0) {
            int old = __hip_atomic_fetch_add(done, 1, __ATOMIC_ACQ_REL, __HIP_MEMORY_SCOPE_AGENT);
            lastFlag = (old == (int)gridDim.x - 1) ? 1 : 0;
        }
        __syncthreads();
        if (lastFlag) {
            // Bs (stg) is free in this path — alias finisher scratch onto it
            float* g  = (float*)&Bs[0][0];   // 512 floats
            float* g2 = g + 512;             // 128 floats
            float* lg = g2 + 128;            // 2 floats
            float invn = 1.0f / (float)nTotal;
            for (int i2 = tid; i2 < 512; i2 += 256)
                g[i2] = __hip_atomic_load(&colsumBase[i2], __ATOMIC_ACQUIRE,
                                          __HIP_MEMORY_SCOPE_AGENT) * invn;
            __syncthreads();
            if (tid < 128) {
                float a2 = bpred[tid];
                for (int i2 = 0; i2 < 512; i2++) a2 += g[i2] * Wpred[i2 * 128 + tid];
                g2[tid] = a2;
            }
            __syncthreads();
            if (tid < 2) {
                float l2 = bcls[tid];
                for (int j = 0; j < 128; j++) l2 += g2[j] * Wcls[j * 2 + tid];
                lg[tid] = l2;
            }
            __syncthreads();
            if (tid == 0) {
                float m = fmaxf(lg[0], lg[1]);
                float e0 = expf(lg[0] - m), e1 = expf(lg[1] - m);
                float s2 = e0 + e1;
                out[0] = e0 / s2;
                out[1] = e1 / s2;
            }
        }
    }
}

// ---------------- launch ----------------

extern "C" void kernel_launch(void* const* d_in, const int* in_sizes, int n_in,
                              void* d_out, int out_size, void* d_ws, size_t ws_size,
                              hipStream_t stream) {
    const float* node_feat = (const float*)d_in[0];
    const float* degree = (const float*)d_in[3];
    const float* Wn     = (const float*)d_in[4];
    const float* bn     = (const float*)d_in[5];
    const float* Wgcn   = (const float*)d_in[8];
    const float* bgcn   = (const float*)d_in[9];
    const float* Wpred  = (const float*)d_in[10];
    const float* bpred  = (const float*)d_in[11];
    const float* Wcls   = (const float*)d_in[12];
    const float* bcls   = (const float*)d_in[13];
    const int*   src    = (const int*)d_in[14];
    const int*   dst    = (const int*)d_in[15];
    float* out = (float*)d_out;

    const int N = in_sizes[3];
    const int E = in_sizes[14];
    (void)n_in; (void)out_size; (void)ws_size;

    char* p = (char*)d_ws;
    auto carve = [&](size_t bytes) { char* r = p; p += (bytes + 255) & ~(size_t)255; return r; };
    // cnt + part + done + colsum carved contiguously -> single memset covers all
    int*   cnt    = (int*)carve((size_t)N * 4);
    int*   part   = (int*)carve(256 * 4);
    int*   done   = (int*)carve(256);                   // 1 int, padded
    float* colsum = (float*)carve(512 * 4);
    uint4* h0g    = (uint4*)carve((size_t)N * H);       // fp8 h0 gather table (128 B/row)
    uint4* hsb0   = (uint4*)carve((size_t)N * H);       // fp8 pre-scaled hidden, ping
    uint4* hsb1   = (uint4*)carve((size_t)N * H);       // fp8 pre-scaled hidden, pong
    bf16*  WnT    = (bf16*)carve((size_t)256 * 128 * 2);
    bf16*  WgT    = (bf16*)carve((size_t)128 * 128 * 2);
    int*   row_ptr= (int*)carve((size_t)(N + 1) * 4);
    int*   nxt    = (int*)carve((size_t)N * 4);
    int*   ssrc   = (int*)carve((size_t)E * 4);

    const int nblk = (N + 255) / 256;
    // zero cnt..colsum in one fill (contiguous carve region: cnt, part, done, colsum)
    hipMemsetAsync(cnt, 0, (size_t)((char*)(colsum + 512) - (char*)cnt), stream);

    // fused: in-degree histogram + chunk partials + weight pre-transpose (scan1 deleted)
    k_setup<<<(E + 255) / 256, 256, 0, stream>>>(dst, cnt, part, E, Wn, Wgcn, WnT, WgT);
    k_scan23<<<nblk, 256, 0, stream>>>(cnt, part, row_ptr, nxt, N, E);

    const int gblk = (N + 63) / 64;
    const int ablk = (N + 15) / 16;
    const int fillBlks = (E + 255) / 256;

    // fused dispatch: bucket-fill (independent) + GEMM0 h0 = node_feat @ Wn + bn
    k_fillgemm0<<<fillBlks + gblk, 256, 0, stream>>>(src, dst, nxt, ssrc, E, fillBlks,
                                                     node_feat, WnT, bn, h0g, colsum, N);

    // fusion: hsb0[v] = (sum_{u->v} h0[u]) / deg[v]
    k_agg0<<<ablk, 256, 0, stream>>>(h0g, row_ptr, ssrc, degree, hsb0, N);

    // fused layers: ping-pong across dispatches; last layer's final block runs the finisher
    k_gemmL<true ><<<gblk, 256, 0, stream>>>(hsb0, row_ptr, ssrc, degree, WgT, bgcn, hsb1,
                                             colsum + 1 * H, N,
                                             nullptr, nullptr, nullptr, nullptr, nullptr,
                                             nullptr, nullptr, 0);
    k_gemmL<true ><<<gblk, 256, 0, stream>>>(hsb1, row_ptr, ssrc, degree, WgT, bgcn, hsb0,
                                             colsum + 2 * H, N,
                                             nullptr, nullptr, nullptr, nullptr, nullptr,
                                             nullptr, nullptr, 0);
    k_gemmL<false><<<gblk, 256, 0, stream>>>(hsb0, row_ptr, ssrc, degree, WgT, bgcn, hsb1,
                                             colsum + 3 * H, N,
                                             colsum, Wpred, bpred, Wcls, bcls, out, done, N);
}